// Round 20
// baseline (190.937 us; speedup 1.0000x reference)
//
#include <hip/hip_runtime.h>
#include <hip/hip_bf16.h>

#define NGRAPH 4096
#define PBLOCKS 768   // 3 persistent blocks per CU

typedef __attribute__((ext_vector_type(8))) short s16x8;
typedef __attribute__((ext_vector_type(4))) float f32x4;
typedef unsigned int u32;

__device__ inline short f2bf(float f) {
  unsigned u = __float_as_uint(f);
  unsigned r = u + 0x7fffu + ((u >> 16) & 1u);
  return (short)(r >> 16);
}

__device__ inline long long getb(const void* b, int i, int is64) {
  if (is64) return ((const long long*)b)[i];
  return (long long)((const int*)b)[i];
}

__device__ inline int lowb(const void* b, int n, long long v, int is64) {
  int lo = 0, hi = n;
  while (lo < hi) {
    int mid = (lo + hi) >> 1;
    if (getb(b, mid, is64) < v) lo = mid + 1; else hi = mid;
  }
  return lo;
}

__device__ inline int batch_is64(const void* batch, int N) {
  // int64 vs int32 materialization probe: an odd 32-bit word index has a zero
  // high word under int64 (values < 2^31), a near-max sorted id under int32.
  int probe = ((N & 1) == 0) ? (N - 1) : (N - 2);
  return (((const int*)batch)[probe] == 0) ? 1 : 0;
}

// Consolidated setup (R19): prepack W1, offs, per-tile meta, zero accumulators.
// meta is now per 16-row tile: {g, lb(g+1), lb(g+2), lb(g+3)}.
__global__ void setup(const float* __restrict__ W1, const void* __restrict__ batch,
                      s16x8* __restrict__ w1p, int* __restrict__ offs,
                      int4* __restrict__ meta, float* __restrict__ pooled,
                      float* __restrict__ segsum, int N, int ntiles,
                      int metaB, int zeroB)
{
  const int b = blockIdx.x, tid = threadIdx.x;
  if (b < 16) {
    // prepack W1 (256x128 fp32, row-major) into B-fragment order.
    // Fragment f = kt*8+ct. Lane l supplies B[k][c], k = kt*32+(l>>4)*8+e,
    // c = ct*16+(l&15).
    int t = b * 256 + tid;
    int f = t >> 6, l = t & 63;
    int kt = f >> 3, ct = f & 7;
    int k0 = kt * 32 + ((l >> 4) * 8);
    int c  = ct * 16 + (l & 15);
    s16x8 v;
    #pragma unroll
    for (int e = 0; e < 8; ++e) v[e] = f2bf(W1[(k0 + e) * 128 + c]);
    w1p[f * 64 + l] = v;
  } else if (b < 33) {
    const int is64 = batch_is64(batch, N);
    int g = (b - 16) * 256 + tid;
    if (g <= NGRAPH) offs[g] = lowb(batch, N, (long long)g, is64);
  } else if (b < 33 + metaB) {
    const int is64 = batch_is64(batch, N);
    int t = (b - 33) * 256 + tid;
    if (t < ntiles) {
      int node = t * 16; if (node >= N) node = N - 1;
      int g = (int)getb(batch, node, is64);
      meta[t] = make_int4(g,
                          lowb(batch, N, (long long)(g + 1), is64),
                          lowb(batch, N, (long long)(g + 2), is64),
                          lowb(batch, N, (long long)(g + 3), is64));
    }
  } else {
    const int zb = b - 33 - metaB;
    float4* p = (float4*)pooled;
    const int tot4 = NGRAPH * 256 / 4;
    for (int i = zb * 256 + tid; i < tot4; i += zeroB * 256)
      p[i] = make_float4(0.f, 0.f, 0.f, 0.f);
    for (int i = zb * 256 + tid; i < NGRAPH; i += zeroB * 256)
      segsum[i] = 0.f;
  }
}

__device__ inline float fast_tanh(float v) {
  v = fminf(fmaxf(v, -15.f), 15.f);
  float e = __expf(2.f * v);
  return __fdividef(e - 1.f, e + 1.f);
}

__device__ inline void dma16(const float* src, char* ldsdst) {
  __builtin_amdgcn_global_load_lds(
      (const __attribute__((address_space(1))) u32*)src,
      (__attribute__((address_space(3))) u32*)ldsdst,
      16, 0, 0);   // 16 B/lane: lane l -> ldsdst + l*16
}

// PERSISTENT DBUF, 16-ROW TILES, 3 blocks/CU.
// vmcnt ISSUE-ORDER discipline replaces register-resident B-frags: per
// iteration the 16 W1-fragment loads (cur) are issued BEFORE the 4 prefetch
// DMAs (next) -- in-order vmcnt drains oldest-first, so the compiler's
// counted waits for the fragments leave the prefetch DMAs in flight through
// the whole compute phase. Frees 128 VGPRs -> 33 KB dbuf tiles fit 3
// blocks/CU at launch_bounds(256,3) (never-spilled cap).
// Phase A: 4-way column split -- wave w owns hidden cols w*32..w*32+31
// (frags 2w, 2w+1) on the tile's 16 rows; 2 MFMA per kt.
// Phase B: pooling from LDS, col = tid, meta-resident segment bounds.
// Raw s_barrier + lgkmcnt only; end-of-iteration vmcnt(0) is the only full
// drain (next tile's data must be resident anyway).
// Scores bounded (|s| <= ||W2||_1 + |b2| ~ 9) -> exp without max.
// Cross-tile segment joins via atomicAdd (buffers zeroed by setup).
__global__ __launch_bounds__(256, 3)
void gate_pool(const float* __restrict__ x, const int4* __restrict__ meta,
               const int* __restrict__ offs,
               const float* __restrict__ b1, const float* __restrict__ W2,
               const float* __restrict__ b2p, const s16x8* __restrict__ w1p,
               float* __restrict__ pooled, float* __restrict__ expout,
               float* __restrict__ segsum, int N, int ntiles)
{
  __shared__ __align__(16) char buf[2][16 * 1024];
  __shared__ float sp[4][16];   // [wave][row] partial scores (32 cols each)
  __shared__ float sw[16];      // exp(score) per row

  const int tid = threadIdx.x;
  const int w = tid >> 6, l = tid & 63;
  const int l15 = l & 15, lg = l >> 4;

  if (blockIdx.x >= ntiles) return;

  float b1v[2], w2v[2];
  #pragma unroll
  for (int ct = 0; ct < 2; ++ct) {
    int c = w * 32 + ct * 16 + l15;
    b1v[ct] = b1[c];
    w2v[ct] = W2[c];
  }
  const float b2s = b2p[0];

  int ti = blockIdx.x;
  int4 M = meta[ti];

  // prologue: stage first tile into buf[0] (wave w rows w, w+4, w+8, w+12)
  {
    const int node0 = ti * 16;
    #pragma unroll
    for (int i = 0; i < 4; ++i) {
      const int r = i * 4 + w;
      int grow = node0 + r;
      if (grow >= N) grow = N - 1;
      dma16(x + (size_t)grow * 256 + ((l ^ (r & 7)) << 2), buf[0] + r * 1024);
    }
  }
  asm volatile("s_waitcnt vmcnt(0)" ::: "memory");
  __builtin_amdgcn_s_barrier();
  __builtin_amdgcn_sched_barrier(0);

  int par = 0;
  for (; ti < ntiles; ti += PBLOCKS) {
    const int node0 = ti * 16;

    // ---- (1) issue cur-tile W1-fragment loads FIRST (oldest in queue) ----
    s16x8 wb[8][2];
    #pragma unroll
    for (int kt = 0; kt < 8; ++kt) {
      wb[kt][0] = w1p[(kt * 8 + w * 2    ) * 64 + l];
      wb[kt][1] = w1p[(kt * 8 + w * 2 + 1) * 64 + l];
    }
    __builtin_amdgcn_sched_barrier(0);

    // ---- (2) then prefetch next tile -> buf^1 (newest; waits for wb
    //      fragments leave these in flight) ----
    const int tnext = ti + PBLOCKS;
    int4 Mnext = M;
    if (tnext < ntiles) {
      Mnext = meta[tnext];
      const int nn0 = tnext * 16;
      char* dst = buf[par ^ 1];
      #pragma unroll
      for (int i = 0; i < 4; ++i) {
        const int r = i * 4 + w;
        int grow = nn0 + r;
        if (grow >= N) grow = N - 1;
        dma16(x + (size_t)grow * 256 + ((l ^ (r & 7)) << 2), dst + r * 1024);
      }
    }
    __builtin_amdgcn_sched_barrier(0);

    const char* tile = buf[par];

    // ---- Phase A: wave w owns cols w*32..+31 on rows 0..15 ----
    {
      const int r0 = l15;
      const char* p0 = tile + r0 * 1024;
      const int s0 = (r0 & 7);
      f32x4 acc0 = {0.f,0.f,0.f,0.f}, acc1 = {0.f,0.f,0.f,0.f};
      #pragma unroll
      for (int kt = 0; kt < 8; ++kt) {
        const int cc = kt * 8 + lg * 2;
        float4 xa = *(const float4*)(p0 + (((cc    ) ^ s0) << 4));
        float4 xb = *(const float4*)(p0 + (((cc + 1) ^ s0) << 4));
        s16x8 a;
        a[0] = f2bf(xa.x); a[1] = f2bf(xa.y); a[2] = f2bf(xa.z); a[3] = f2bf(xa.w);
        a[4] = f2bf(xb.x); a[5] = f2bf(xb.y); a[6] = f2bf(xb.z); a[7] = f2bf(xb.w);
        acc0 = __builtin_amdgcn_mfma_f32_16x16x32_bf16(a, wb[kt][0], acc0, 0, 0, 0);
        acc1 = __builtin_amdgcn_mfma_f32_16x16x32_bf16(a, wb[kt][1], acc1, 0, 0, 0);
      }
      // h = tanh(acc+b1); partial over this wave's 32 cols.
      // D layout: row = 4*lg + r, col-in-frag = l15.
      float part[4];
      #pragma unroll
      for (int r = 0; r < 4; ++r) {
        part[r] = (w == 0) ? b2s : 0.f;
        part[r] += fast_tanh(acc0[r] + b1v[0]) * w2v[0];
        part[r] += fast_tanh(acc1[r] + b1v[1]) * w2v[1];
      }
      #pragma unroll
      for (int m = 1; m <= 8; m <<= 1) {
        #pragma unroll
        for (int r = 0; r < 4; ++r) part[r] += __shfl_xor(part[r], m, 64);
      }
      if (l15 == 0) {
        #pragma unroll
        for (int r = 0; r < 4; ++r)
          sp[w][lg * 4 + r] = part[r];
      }
    }
    asm volatile("s_waitcnt lgkmcnt(0)" ::: "memory");
    __builtin_amdgcn_s_barrier();
    __builtin_amdgcn_sched_barrier(0);

    // combine 4 wave-partials, exponentiate (no max: |score| <= ~9), store
    if (tid < 16) {
      int node = node0 + tid;
      float e = 0.f;
      if (node < N) {
        e = __expf(sp[0][tid] + sp[1][tid] + sp[2][tid] + sp[3][tid]);
        expout[node] = e;
      }
      sw[tid] = e;
    }
    asm volatile("s_waitcnt lgkmcnt(0)" ::: "memory");
    __builtin_amdgcn_s_barrier();
    __builtin_amdgcn_sched_barrier(0);

    // ---- Phase B: pooling from LDS, col = tid; meta-resident offs ----
    {
      const int nmax = min(16, N - node0);
      int g = M.x;
      int nb = M.y;
      int crossing = 0;
      const int ccb = tid >> 2, cib = (tid & 3) << 2;
      int r = 0;
      while (r < nmax) {
        const int rend = min(nb - node0, nmax);
        float pacc = 0.f, wsum = 0.f;
        for (; r + 4 <= rend; r += 4) {
          float xv[4], wv[4];
          #pragma unroll
          for (int u = 0; u < 4; ++u) {
            const int rr = r + u;
            xv[u] = *(const float*)(tile + rr * 1024 + (((ccb ^ (rr & 7)) << 4) | cib));
            wv[u] = sw[rr];
          }
          #pragma unroll
          for (int u = 0; u < 4; ++u) {
            pacc += wv[u] * xv[u];
            wsum += wv[u];
          }
        }
        for (; r < rend; ++r) {
          float wv = sw[r];
          pacc += wv * *(const float*)(tile + r * 1024 + (((ccb ^ (r & 7)) << 4) | cib));
          wsum += wv;
        }
        if (wsum > 0.f) {
          atomicAdd(&pooled[(size_t)g * 256 + tid], pacc);
          if (tid == 0) atomicAdd(&segsum[g], wsum);
        }
        if (rend >= nmax) break;
        ++g; ++crossing;
        nb = (crossing == 1) ? M.z
           : (crossing == 2) ? M.w
           : offs[min(g + 1, NGRAPH)];   // lazy fallback (rare)
      }
    }

    asm volatile("s_waitcnt vmcnt(0)" ::: "memory");  // next tile resident
    __builtin_amdgcn_s_barrier();
    __builtin_amdgcn_sched_barrier(0);
    M = Mnext;
    par ^= 1;
  }
}

// Finalize: pooled /= segsum (0 for empty graphs), weights = exp/segsum[batch].
__global__ void finalize(float* __restrict__ pooled, float* __restrict__ wts,
                         const float* __restrict__ segsum,
                         const void* __restrict__ batch, int N)
{
  int f = blockIdx.x * 256 + threadIdx.x;
  if (f < NGRAPH * 256) {
    int g = f >> 8;
    float s = segsum[g];
    pooled[f] = (s > 0.f) ? pooled[f] / s : 0.f;
  } else {
    int n = f - NGRAPH * 256;
    if (n < N) {
      const int is64 = batch_is64(batch, N);
      int g = (int)getb(batch, n, is64);
      wts[n] = wts[n] / segsum[g];
    }
  }
}

extern "C" void kernel_launch(void* const* d_in, const int* in_sizes, int n_in,
                              void* d_out, int out_size, void* d_ws, size_t ws_size,
                              hipStream_t stream) {
  const float* x     = (const float*)d_in[0];
  const void*  batch = d_in[1];
  const float* W1    = (const float*)d_in[2];
  const float* b1    = (const float*)d_in[3];
  const float* W2    = (const float*)d_in[4];
  const float* b2    = (const float*)d_in[5];
  const int N = in_sizes[0] / 256;
  const int ntiles = (N + 15) / 16;

  float* pooled = (float*)d_out;                          // 4096*256
  float* wout   = (float*)d_out + (size_t)NGRAPH * 256;   // N: exp(s), then weights
  s16x8* w1p    = (s16x8*)d_ws;                           // 64 KB
  int*   offs   = (int*)((char*)d_ws + 64 * 1024);        // 4097 * 4 B
  float* segsum = (float*)((char*)d_ws + 96 * 1024);      // 4096 * 4 B
  int4*  meta   = (int4*)((char*)d_ws + 128 * 1024);      // ntiles * 16 B (~500 KB)

  const int metaB = (ntiles + 255) / 256;
  const int zeroB = 64;
  const int setupB = 33 + metaB + zeroB;

  setup<<<setupB, 256, 0, stream>>>(W1, batch, w1p, offs, meta,
                                    pooled, segsum, N, ntiles, metaB, zeroB);
  gate_pool<<<PBLOCKS, 256, 0, stream>>>(x, meta, offs, b1, W2, b2, w1p,
                                         pooled, wout, segsum, N, ntiles);
  const int tot = NGRAPH * 256 + N;
  finalize<<<(tot + 255) / 256, 256, 0, stream>>>(pooled, wout, segsum, batch, N);
}

// Round 21
// 177.769 us; speedup vs baseline: 1.0741x; 1.0741x over previous
//
#include <hip/hip_runtime.h>
#include <hip/hip_bf16.h>

#define NGRAPH 4096
#define PBLOCKS 512   // 2 persistent blocks per CU

typedef __attribute__((ext_vector_type(8))) short s16x8;
typedef __attribute__((ext_vector_type(4))) float f32x4;
typedef unsigned int u32;

__device__ inline short f2bf(float f) {
  unsigned u = __float_as_uint(f);
  unsigned r = u + 0x7fffu + ((u >> 16) & 1u);
  return (short)(r >> 16);
}

__device__ inline long long getb(const void* b, int i, int is64) {
  if (is64) return ((const long long*)b)[i];
  return (long long)((const int*)b)[i];
}

__device__ inline int lowb(const void* b, int n, long long v, int is64) {
  int lo = 0, hi = n;
  while (lo < hi) {
    int mid = (lo + hi) >> 1;
    if (getb(b, mid, is64) < v) lo = mid + 1; else hi = mid;
  }
  return lo;
}

__device__ inline int batch_is64(const void* batch, int N) {
  // int64 vs int32 materialization probe: an odd 32-bit word index has a zero
  // high word under int64 (values < 2^31), a near-max sorted id under int32.
  int probe = ((N & 1) == 0) ? (N - 1) : (N - 2);
  return (((const int*)batch)[probe] == 0) ? 1 : 0;
}

// ONE consolidated setup kernel (replaces prepack + seg_offsets + tile_meta +
// 2 hipMemsetAsync -> cuts 4 graph nodes of launch/serialization overhead).
// Block partition:
//   [0,16):          prepack W1 -> bf16 MFMA B-fragment order
//   [16,33):         offs[g] = lower_bound(batch, g)
//   [33,33+metaB):   meta[t] = {g, lb(g+1), lb(g+2), lb(g+3)} (own searches,
//                    no dependency on offs[])
//   [33+metaB, ...): zero pooled (float4 grid-stride) + segsum
__global__ void setup(const float* __restrict__ W1, const void* __restrict__ batch,
                      s16x8* __restrict__ w1p, int* __restrict__ offs,
                      int4* __restrict__ meta, float* __restrict__ pooled,
                      float* __restrict__ segsum, int N, int ntiles,
                      int metaB, int zeroB)
{
  const int b = blockIdx.x, tid = threadIdx.x;
  if (b < 16) {
    // prepack W1 (256x128 fp32, row-major) into B-fragment order.
    // Fragment f = kt*8+ct. Lane l supplies B[k][c], k = kt*32+(l>>4)*8+e,
    // c = ct*16+(l&15).
    int t = b * 256 + tid;
    int f = t >> 6, l = t & 63;
    int kt = f >> 3, ct = f & 7;
    int k0 = kt * 32 + ((l >> 4) * 8);
    int c  = ct * 16 + (l & 15);
    s16x8 v;
    #pragma unroll
    for (int e = 0; e < 8; ++e) v[e] = f2bf(W1[(k0 + e) * 128 + c]);
    w1p[f * 64 + l] = v;
  } else if (b < 33) {
    const int is64 = batch_is64(batch, N);
    int g = (b - 16) * 256 + tid;
    if (g <= NGRAPH) offs[g] = lowb(batch, N, (long long)g, is64);
  } else if (b < 33 + metaB) {
    const int is64 = batch_is64(batch, N);
    int t = (b - 33) * 256 + tid;
    if (t < ntiles) {
      int node = t * 32; if (node >= N) node = N - 1;
      int g = (int)getb(batch, node, is64);
      meta[t] = make_int4(g,
                          lowb(batch, N, (long long)(g + 1), is64),
                          lowb(batch, N, (long long)(g + 2), is64),
                          lowb(batch, N, (long long)(g + 3), is64));
    }
  } else {
    const int zb = b - 33 - metaB;
    float4* p = (float4*)pooled;
    const int tot4 = NGRAPH * 256 / 4;
    for (int i = zb * 256 + tid; i < tot4; i += zeroB * 256)
      p[i] = make_float4(0.f, 0.f, 0.f, 0.f);
    for (int i = zb * 256 + tid; i < NGRAPH; i += zeroB * 256)
      segsum[i] = 0.f;
  }
}

__device__ inline float fast_tanh(float v) {
  v = fminf(fmaxf(v, -15.f), 15.f);
  float e = __expf(2.f * v);
  return __fdividef(e - 1.f, e + 1.f);
}

__device__ inline void dma16(const float* src, char* ldsdst) {
  __builtin_amdgcn_global_load_lds(
      (const __attribute__((address_space(1))) u32*)src,
      (__attribute__((address_space(3))) u32*)ldsdst,
      16, 0, 0);   // 16 B/lane: lane l -> ldsdst + l*16
}

// PERSISTENT DBUF: 512 blocks (2/CU) grid-stride over 32-row tiles.
// Steady-state iteration:
//   [ld int4 meta(next)] [issue 8 DMAs(next) -> buf^1]
//   [compute cur: phase A (MFMA, LDS+reg only), exp, phase B]
//   [vmcnt(0); s_barrier]
// No consumed VMEM sits between prefetch-issue and tile-end (B-frags in
// registers, per-tile segment metadata preloaded), so no compiler wait
// drains the prefetch. Raw s_barrier + lgkmcnt only (never __syncthreads).
// Scores bounded (|s| <= ||W2||_1 + |b2| ~ 9) -> exp without max.
// Cross-tile segment joins via atomicAdd (buffers zeroed by setup).
__global__ __launch_bounds__(256, 2)
void gate_pool(const float* __restrict__ x, const int4* __restrict__ meta,
               const int* __restrict__ offs,
               const float* __restrict__ b1, const float* __restrict__ W2,
               const float* __restrict__ b2p, const s16x8* __restrict__ w1p,
               float* __restrict__ pooled, float* __restrict__ expout,
               float* __restrict__ segsum, int N, int ntiles)
{
  __shared__ __align__(16) char buf[2][32 * 1024];
  __shared__ float sp[2][32];   // [colhalf][row] partial scores
  __shared__ float sw[32];      // exp(score) per row

  const int tid = threadIdx.x;
  const int w = tid >> 6, l = tid & 63;
  const int colhalf = w & 1, wp = w >> 1;
  const int l15 = l & 15, lg = l >> 4;

  if (blockIdx.x >= ntiles) return;

  // ---- one-time preloads (all VMEM, before the pipeline starts) ----
  s16x8 bf[4][8];               // this wave's 32 B-fragments (128 VGPR)
  #pragma unroll
  for (int ctl = 0; ctl < 4; ++ctl)
    #pragma unroll
    for (int kt = 0; kt < 8; ++kt)
      bf[ctl][kt] = w1p[(kt * 8 + colhalf * 4 + ctl) * 64 + l];

  float b1v[4], w2v[4];
  #pragma unroll
  for (int ct = 0; ct < 4; ++ct) {
    int c = colhalf * 64 + ct * 16 + l15;
    b1v[ct] = b1[c];
    w2v[ct] = W2[c];
  }
  const float b2s = b2p[0];

  int ti = blockIdx.x;
  int4 M = meta[ti];

  // prologue: stage first tile into buf[0]
  {
    const int node0 = ti * 32;
    #pragma unroll
    for (int i = 0; i < 8; ++i) {
      const int r = i * 4 + w;
      int grow = node0 + r;
      if (grow >= N) grow = N - 1;
      dma16(x + (size_t)grow * 256 + ((l ^ (r & 7)) << 2), buf[0] + r * 1024);
    }
  }
  asm volatile("s_waitcnt vmcnt(0)" ::: "memory");
  __builtin_amdgcn_s_barrier();
  __builtin_amdgcn_sched_barrier(0);

  int par = 0;
  for (; ti < ntiles; ti += PBLOCKS) {
    const int tnext = ti + PBLOCKS;
    int4 Mnext = M;
    if (tnext < ntiles) {
      Mnext = meta[tnext];                       // older than the DMAs below:
      const int nn0 = tnext * 32;                // its wait won't drain them
      char* dst = buf[par ^ 1];
      #pragma unroll
      for (int i = 0; i < 8; ++i) {
        const int r = i * 4 + w;
        int grow = nn0 + r;
        if (grow >= N) grow = N - 1;
        dma16(x + (size_t)grow * 256 + ((l ^ (r & 7)) << 2), dst + r * 1024);
      }
    }
    __builtin_amdgcn_sched_barrier(0);

    const char* tile = buf[par];
    const int node0 = ti * 32;

    // ---- Phase A: MFMA scores; pair wp owns rows wp*16..+15 (LDS+regs) ----
    {
      const int r0 = wp * 16 + l15;
      const char* p0 = tile + r0 * 1024;
      const int s0 = (r0 & 7);
      f32x4 acc0 = {0.f,0.f,0.f,0.f}, acc1 = {0.f,0.f,0.f,0.f};
      f32x4 acc2 = {0.f,0.f,0.f,0.f}, acc3 = {0.f,0.f,0.f,0.f};
      #pragma unroll
      for (int kt = 0; kt < 8; ++kt) {
        const int cc = kt * 8 + lg * 2;
        float4 xa = *(const float4*)(p0 + (((cc    ) ^ s0) << 4));
        float4 xb = *(const float4*)(p0 + (((cc + 1) ^ s0) << 4));
        s16x8 a;
        a[0] = f2bf(xa.x); a[1] = f2bf(xa.y); a[2] = f2bf(xa.z); a[3] = f2bf(xa.w);
        a[4] = f2bf(xb.x); a[5] = f2bf(xb.y); a[6] = f2bf(xb.z); a[7] = f2bf(xb.w);
        acc0 = __builtin_amdgcn_mfma_f32_16x16x32_bf16(a, bf[0][kt], acc0, 0, 0, 0);
        acc1 = __builtin_amdgcn_mfma_f32_16x16x32_bf16(a, bf[1][kt], acc1, 0, 0, 0);
        acc2 = __builtin_amdgcn_mfma_f32_16x16x32_bf16(a, bf[2][kt], acc2, 0, 0, 0);
        acc3 = __builtin_amdgcn_mfma_f32_16x16x32_bf16(a, bf[3][kt], acc3, 0, 0, 0);
      }
      // h = tanh(acc+b1); partial score over this wave's 64 cols.
      // D layout: node-in-tile = 4*lg + r, hidden-col = ct*16 + l15.
      float part[4];
      #pragma unroll
      for (int r = 0; r < 4; ++r) {
        part[r] = colhalf ? 0.f : b2s;
        part[r] += fast_tanh(acc0[r] + b1v[0]) * w2v[0];
        part[r] += fast_tanh(acc1[r] + b1v[1]) * w2v[1];
        part[r] += fast_tanh(acc2[r] + b1v[2]) * w2v[2];
        part[r] += fast_tanh(acc3[r] + b1v[3]) * w2v[3];
      }
      #pragma unroll
      for (int m = 1; m <= 8; m <<= 1) {
        #pragma unroll
        for (int r = 0; r < 4; ++r) part[r] += __shfl_xor(part[r], m, 64);
      }
      if (l15 == 0) {
        #pragma unroll
        for (int r = 0; r < 4; ++r)
          sp[colhalf][wp * 16 + lg * 4 + r] = part[r];
      }
    }
    asm volatile("s_waitcnt lgkmcnt(0)" ::: "memory");
    __builtin_amdgcn_s_barrier();
    __builtin_amdgcn_sched_barrier(0);

    // combine halves, exponentiate (no max: |score| <= ~9), store
    if (tid < 32) {
      int node = node0 + tid;
      float e = 0.f;
      if (node < N) {
        e = __expf(sp[0][tid] + sp[1][tid]);
        expout[node] = e;
      }
      sw[tid] = e;
    }
    asm volatile("s_waitcnt lgkmcnt(0)" ::: "memory");
    __builtin_amdgcn_s_barrier();
    __builtin_amdgcn_sched_barrier(0);

    // ---- Phase B: pooling from LDS, col = tid; meta-resident offs ----
    {
      const int nmax = min(32, N - node0);
      int g = M.x;
      int nb = M.y;
      int crossing = 0;
      const int ccb = tid >> 2, cib = (tid & 3) << 2;
      int r = 0;
      while (r < nmax) {
        const int rend = min(nb - node0, nmax);
        float pacc = 0.f, wsum = 0.f;
        for (; r + 8 <= rend; r += 8) {
          float xv[8], wv[8];
          #pragma unroll
          for (int u = 0; u < 8; ++u) {
            const int rr = r + u;
            xv[u] = *(const float*)(tile + rr * 1024 + (((ccb ^ (rr & 7)) << 4) | cib));
            wv[u] = sw[rr];
          }
          #pragma unroll
          for (int u = 0; u < 8; ++u) {
            pacc += wv[u] * xv[u];
            wsum += wv[u];
          }
        }
        for (; r < rend; ++r) {
          float wv = sw[r];
          pacc += wv * *(const float*)(tile + r * 1024 + (((ccb ^ (r & 7)) << 4) | cib));
          wsum += wv;
        }
        if (wsum > 0.f) {
          atomicAdd(&pooled[(size_t)g * 256 + tid], pacc);
          if (tid == 0) atomicAdd(&segsum[g], wsum);
        }
        if (rend >= nmax) break;
        ++g; ++crossing;
        nb = (crossing == 1) ? M.z
           : (crossing == 2) ? M.w
           : offs[min(g + 1, NGRAPH)];   // lazy fallback (rare)
      }
    }

    asm volatile("s_waitcnt vmcnt(0)" ::: "memory");  // residual prefetch drain
    __builtin_amdgcn_s_barrier();
    __builtin_amdgcn_sched_barrier(0);
    M = Mnext;
    par ^= 1;
  }
}

// Finalize: pooled /= segsum (0 for empty graphs), weights = exp/segsum[batch].
__global__ void finalize(float* __restrict__ pooled, float* __restrict__ wts,
                         const float* __restrict__ segsum,
                         const void* __restrict__ batch, int N)
{
  int f = blockIdx.x * 256 + threadIdx.x;
  if (f < NGRAPH * 256) {
    int g = f >> 8;
    float s = segsum[g];
    pooled[f] = (s > 0.f) ? pooled[f] / s : 0.f;
  } else {
    int n = f - NGRAPH * 256;
    if (n < N) {
      const int is64 = batch_is64(batch, N);
      int g = (int)getb(batch, n, is64);
      wts[n] = wts[n] / segsum[g];
    }
  }
}

extern "C" void kernel_launch(void* const* d_in, const int* in_sizes, int n_in,
                              void* d_out, int out_size, void* d_ws, size_t ws_size,
                              hipStream_t stream) {
  const float* x     = (const float*)d_in[0];
  const void*  batch = d_in[1];
  const float* W1    = (const float*)d_in[2];
  const float* b1    = (const float*)d_in[3];
  const float* W2    = (const float*)d_in[4];
  const float* b2    = (const float*)d_in[5];
  const int N = in_sizes[0] / 256;
  const int ntiles = (N + 31) / 32;

  float* pooled = (float*)d_out;                          // 4096*256
  float* wout   = (float*)d_out + (size_t)NGRAPH * 256;   // N: exp(s), then weights
  s16x8* w1p    = (s16x8*)d_ws;                           // 64 KB
  int*   offs   = (int*)((char*)d_ws + 64 * 1024);        // 4097 * 4 B
  float* segsum = (float*)((char*)d_ws + 96 * 1024);      // 4096 * 4 B
  int4*  meta   = (int4*)((char*)d_ws + 128 * 1024);      // ntiles * 16 B (~250 KB)

  const int metaB = (ntiles + 255) / 256;
  const int zeroB = 64;
  const int setupB = 33 + metaB + zeroB;

  setup<<<setupB, 256, 0, stream>>>(W1, batch, w1p, offs, meta,
                                    pooled, segsum, N, ntiles, metaB, zeroB);
  gate_pool<<<PBLOCKS, 256, 0, stream>>>(x, meta, offs, b1, W2, b2, w1p,
                                         pooled, wout, segsum, N, ntiles);
  const int tot = NGRAPH * 256 + N;
  finalize<<<(tot + 255) / 256, 256, 0, stream>>>(pooled, wout, segsum, batch, N);
}